// Round 12
// baseline (613.675 us; speedup 1.0000x reference)
//
#include <hip/hip_runtime.h>
#include <math.h>

#define NN 50000
#define NE 800000
#define IPSET 1563          // M2 items per set (ceil(50000/32))
#define NITEMS (2 * IPSET)  // enc work items (M2: 32 rows each)
#define SLOTS 64            // bucket capacity per row (Poisson(16): P(>=64) ~ 1e-18)

typedef __attribute__((ext_vector_type(8))) short bf16x8;
typedef __attribute__((ext_vector_type(4))) float f32x4;

__device__ __forceinline__ ushort f2bf(float f) {
    union { float f; unsigned u; } v; v.f = f;
    unsigned r = v.u + 0x7FFFu + ((v.u >> 16) & 1u);   // RNE
    return (ushort)(r >> 16);
}

__device__ __forceinline__ float bf2f(ushort u) {
    union { unsigned u; float f; } v; v.u = ((unsigned)u) << 16;
    return v.f;
}

// packed bf16 convert: 1 VALU inst per 2 floats (no builtin on gfx950 -> inline asm)
__device__ __forceinline__ unsigned cvtpk(float lo, float hi) {
    unsigned r;
    asm("v_cvt_pk_bf16_f32 %0, %1, %2" : "=v"(r) : "v"(lo), "v"(hi));
    return r;
}

__device__ __forceinline__ bf16x8 cvt8pk(const float* v) {
    union { unsigned u[4]; bf16x8 b; } o;
    o.u[0] = cvtpk(v[0], v[1]);
    o.u[1] = cvtpk(v[2], v[3]);
    o.u[2] = cvtpk(v[4], v[5]);
    o.u[3] = cvtpk(v[6], v[7]);
    return o.b;
}

// ============ fragment precompute + cnt zero (one launch) ============
__device__ __forceinline__ void frag_one(const float* __restrict__ src, ushort* __restrict__ dst,
                                         int K, int Nc, int t) {
    int nct = (Nc + 15) >> 4;
    int lane = t & 63, rest = t >> 6;
    int ct = rest % nct, g = rest / nct;
    int col = ct * 16 + (lane & 15);
    int kb = g * 32 + (lane >> 4) * 8;
    ushort u[8];
    #pragma unroll
    for (int j = 0; j < 8; ++j) {
        int k = kb + j;
        float v = (k < K && col < Nc) ? src[(size_t)k * Nc + col] : 0.f;
        u[j] = f2bf(v);
    }
    *(bf16x8*)&dst[(size_t)t * 8] = *(bf16x8*)u;
}

__global__ __launch_bounds__(256) void frag_zero(
    const float* __restrict__ s0, ushort* __restrict__ d0, int K0, int N0, int n0,
    const float* __restrict__ s1, ushort* __restrict__ d1, int K1, int N1, int n1,
    const float* __restrict__ s2, ushort* __restrict__ d2, int K2, int N2, int n2,
    const float* __restrict__ s3, ushort* __restrict__ d3, int K3, int N3, int n3,
    int* __restrict__ zbuf, int nz) {
    int t = blockIdx.x * 256 + threadIdx.x;
    if (t < n0) { frag_one(s0, d0, K0, N0, t); return; } t -= n0;
    if (t < n1) { frag_one(s1, d1, K1, N1, t); return; } t -= n1;
    if (t < n2) { frag_one(s2, d2, K2, N2, t); return; } t -= n2;
    if (t < n3) { frag_one(s3, d3, K3, N3, t); return; } t -= n3;
    if (t < nz) zbuf[t] = 0;
}

// ============ encoder GEMM item (M2; cvt_pk staging) ============
__device__ __forceinline__ void enc_item(
    const float* __restrict__ A, const ushort* __restrict__ Bf, ushort* __restrict__ C,
    int K, int item, int lane) {
    const int M = NN;
    const int klo = (lane >> 4) * 8;
    int r0 = item * 32 + (lane & 15);
    int r1 = r0 + 16;
    const float* ap0 = A + (size_t)(r0 < M ? r0 : M - 1) * K;
    const float* ap1 = A + (size_t)(r1 < M ? r1 : M - 1) * K;
    const bf16x8* bv = (const bf16x8*)Bf;
    const int ng = (K + 31) >> 5;
    f32x4 acc[2][4] = {};
    #pragma unroll 2
    for (int g = 0; g < ng; ++g) {
        int kg = g * 32 + klo;
        bf16x8 af[2];
        #pragma unroll
        for (int tt = 0; tt < 2; ++tt) {
            const float* ap = tt ? ap1 : ap0;
            float v[8];
            if (kg + 7 < K) {
                f32x4 a = *(const f32x4*)(ap + kg);
                f32x4 b = *(const f32x4*)(ap + kg + 4);
                v[0] = a.x; v[1] = a.y; v[2] = a.z; v[3] = a.w;
                v[4] = b.x; v[5] = b.y; v[6] = b.z; v[7] = b.w;
            } else {
                #pragma unroll
                for (int j = 0; j < 8; ++j) v[j] = (kg + j < K) ? ap[kg + j] : 0.f;
            }
            af[tt] = cvt8pk(v);
        }
        #pragma unroll
        for (int ct = 0; ct < 4; ++ct) {
            bf16x8 b = bv[(g * 4 + ct) * 64 + lane];
            acc[0][ct] = __builtin_amdgcn_mfma_f32_16x16x32_bf16(b, af[0], acc[0][ct], 0, 0, 0);
            acc[1][ct] = __builtin_amdgcn_mfma_f32_16x16x32_bf16(b, af[1], acc[1][ct], 0, 0, 0);
        }
    }
    const int cq = (lane >> 4) * 4;
    #pragma unroll
    for (int tt = 0; tt < 2; ++tt) {
        int row = item * 32 + tt * 16 + (lane & 15);
        if (row < M) {
            #pragma unroll
            for (int ct = 0; ct < 4; ++ct) {
                uint2 uu;
                uu.x = cvtpk(acc[tt][ct][0], acc[tt][ct][1]);
                uu.y = cvtpk(acc[tt][ct][2], acc[tt][ct][3]);
                *(uint2*)&C[(size_t)row * 64 + ct * 16 + cq] = uu;
            }
        }
    }
}

// ============ K1: bucket scatter (grid-stride) || ALL enc items ============
__global__ __launch_bounds__(256) void k1_bucket_enc(
    const int* __restrict__ r1, const int* __restrict__ ce1, const float* __restrict__ w1,
    int* __restrict__ cnt1, int2* __restrict__ buf1,
    const int* __restrict__ r2, const int* __restrict__ ce2, const float* __restrict__ w2,
    int* __restrict__ cnt2, int2* __restrict__ buf2, int nsb,
    const float* __restrict__ A1, const ushort* __restrict__ Bf1, ushort* __restrict__ C1, int K1,
    const float* __restrict__ A2, const ushort* __restrict__ Bf2, ushort* __restrict__ C2, int K2) {
    if ((int)blockIdx.x < nsb) {
        int stride = nsb * 256;
        for (int i = blockIdx.x * 256 + threadIdx.x; i < 2 * NE; i += stride) {
            if (i < NE) {
                int r = r1[i];
                int s = atomicAdd(&cnt1[r], 1);
                if (s < SLOTS) buf1[(size_t)r * SLOTS + s] = make_int2(ce1[i], __float_as_int(w1[i]));
            } else {
                int j = i - NE;
                int r = r2[j];
                int s = atomicAdd(&cnt2[r], 1);
                if (s < SLOTS) buf2[(size_t)r * SLOTS + s] = make_int2(ce2[j], __float_as_int(w2[j]));
            }
        }
        return;
    }
    int item = (blockIdx.x - nsb) * 4 + (threadIdx.x >> 6);
    if (item < NITEMS) {
        int lane = threadIdx.x & 63;
        if (item < IPSET) enc_item(A1, Bf1, C1, K1, item, lane);
        else              enc_item(A2, Bf2, C2, K2, item - IPSET, lane);
    }
}

// ============ dual-cursor interleaved spmm gather (bucket layout) ============
__device__ __forceinline__ void spmm_row2(
    const int2* __restrict__ p1, int n1, const ushort* __restrict__ x1,
    const int2* __restrict__ p2, int n2, const ushort* __restrict__ x2,
    int lane, float& acc1o, float& acc2o) {
    float acc1 = 0.f, acc2 = 0.f;
    int i1 = 0, i2 = 0;
    while (i1 + 3 < n1 && i2 + 3 < n2) {
        int2 a0 = p1[i1], a1 = p1[i1 + 1], a2 = p1[i1 + 2], a3 = p1[i1 + 3];
        int2 b0 = p2[i2], b1 = p2[i2 + 1], b2 = p2[i2 + 2], b3 = p2[i2 + 3];
        float ga0 = bf2f(x1[(size_t)a0.x * 64 + lane]);
        float gb0 = bf2f(x2[(size_t)b0.x * 64 + lane]);
        float ga1 = bf2f(x1[(size_t)a1.x * 64 + lane]);
        float gb1 = bf2f(x2[(size_t)b1.x * 64 + lane]);
        float ga2 = bf2f(x1[(size_t)a2.x * 64 + lane]);
        float gb2 = bf2f(x2[(size_t)b2.x * 64 + lane]);
        float ga3 = bf2f(x1[(size_t)a3.x * 64 + lane]);
        float gb3 = bf2f(x2[(size_t)b3.x * 64 + lane]);
        acc1 += __int_as_float(a0.y) * ga0; acc2 += __int_as_float(b0.y) * gb0;
        acc1 += __int_as_float(a1.y) * ga1; acc2 += __int_as_float(b1.y) * gb1;
        acc1 += __int_as_float(a2.y) * ga2; acc2 += __int_as_float(b2.y) * gb2;
        acc1 += __int_as_float(a3.y) * ga3; acc2 += __int_as_float(b3.y) * gb3;
        i1 += 4; i2 += 4;
    }
    for (; i1 + 3 < n1; i1 += 4) {
        int2 a0 = p1[i1], a1 = p1[i1 + 1], a2 = p1[i1 + 2], a3 = p1[i1 + 3];
        float g0 = bf2f(x1[(size_t)a0.x * 64 + lane]);
        float g1 = bf2f(x1[(size_t)a1.x * 64 + lane]);
        float g2 = bf2f(x1[(size_t)a2.x * 64 + lane]);
        float g3 = bf2f(x1[(size_t)a3.x * 64 + lane]);
        acc1 += __int_as_float(a0.y) * g0; acc1 += __int_as_float(a1.y) * g1;
        acc1 += __int_as_float(a2.y) * g2; acc1 += __int_as_float(a3.y) * g3;
    }
    for (; i2 + 3 < n2; i2 += 4) {
        int2 b0 = p2[i2], b1 = p2[i2 + 1], b2 = p2[i2 + 2], b3 = p2[i2 + 3];
        float g0 = bf2f(x2[(size_t)b0.x * 64 + lane]);
        float g1 = bf2f(x2[(size_t)b1.x * 64 + lane]);
        float g2 = bf2f(x2[(size_t)b2.x * 64 + lane]);
        float g3 = bf2f(x2[(size_t)b3.x * 64 + lane]);
        acc2 += __int_as_float(b0.y) * g0; acc2 += __int_as_float(b1.y) * g1;
        acc2 += __int_as_float(b2.y) * g2; acc2 += __int_as_float(b3.y) * g3;
    }
    for (; i1 < n1; ++i1) {
        int2 p = p1[i1];
        acc1 += __int_as_float(p.y) * bf2f(x1[(size_t)p.x * 64 + lane]);
    }
    for (; i2 < n2; ++i2) {
        int2 p = p2[i2];
        acc2 += __int_as_float(p.y) * bf2f(x2[(size_t)p.x * 64 + lane]);
    }
    acc1o = acc1; acc2o = acc2;
}

// ============ fused encoder-spmm + attention, wave per node ============
__global__ __launch_bounds__(256) void spmm_attn(
    const int* __restrict__ cnt1, const int2* __restrict__ buf1, const ushort* __restrict__ x1,
    const int* __restrict__ cnt2, const int2* __restrict__ buf2, const ushort* __restrict__ x2,
    const float* __restrict__ Wo, const float* __restrict__ uo,
    float* __restrict__ e1, float* __restrict__ e2,
    float* __restrict__ emb, ushort* __restrict__ embb, float* __restrict__ alpha) {
    const int lane = threadIdx.x & 63;
    const int node = (blockIdx.x * 256 + threadIdx.x) >> 6;
    if (node >= NN) return;

    int n1 = cnt1[node]; if (n1 > SLOTS) n1 = SLOTS;
    int n2 = cnt2[node]; if (n2 > SLOTS) n2 = SLOTS;
    float ev0, ev1;
    spmm_row2(buf1 + (size_t)node * SLOTS, n1, x1,
              buf2 + (size_t)node * SLOTS, n2, x2, lane, ev0, ev1);

    float acc1 = 0.f, acc2 = 0.f;
    #pragma unroll 8
    for (int k = 0; k < 64; ++k) {
        float wv = Wo[k * 64 + lane];
        acc1 = fmaf(__shfl(ev0, k), wv, acc1);
        acc2 = fmaf(__shfl(ev1, k), wv, acc2);
    }
    float u = uo[lane];
    float t1 = tanhf(acc1) * u;
    float t2 = tanhf(acc2) * u;
    #pragma unroll
    for (int off = 32; off; off >>= 1) {
        t1 += __shfl_xor(t1, off);
        t2 += __shfl_xor(t2, off);
    }
    float m = fmaxf(t1, t2);
    float a1 = expf(t1 - m), a2 = expf(t2 - m);
    float sden = a1 + a2;
    a1 /= sden; a2 /= sden;

    const size_t base = (size_t)node * 64;
    float ec = a1 * ev0 + a2 * ev1;
    e1[base + lane] = ev0;
    e2[base + lane] = ev1;
    emb[base + lane] = ec;
    embb[base + lane] = f2bf(ec);
    if (lane == 0) *(float2*)&alpha[(size_t)node * 2] = make_float2(a1, a2);
}

// ============ fused decoder: spmm (both sets, 32 rows/block) + set-1 GEMM ============
// phase 1: 4 waves x 8 rows spmm -> s1 to LDS (XOR-swizzled), s2 to global ws.
// phase 2: waves split the 125 column tiles of d1; A-frags from LDS.
__global__ __launch_bounds__(256) void fused_dec1(
    const int* __restrict__ cnt1, const int2* __restrict__ buf1,
    const int* __restrict__ cnt2, const int2* __restrict__ buf2,
    const ushort* __restrict__ xb, ushort* __restrict__ s2b,
    const ushort* __restrict__ Wf1, float* __restrict__ C1) {
    __shared__ ushort sm1[32 * 64];   // 4 KB, swizzled: idx = lr*64 + (k ^ ((lr&7)<<3))
    const int lane = threadIdx.x & 63;
    const int wvid = threadIdx.x >> 6;
    const int rbase = blockIdx.x * 32;

    #pragma unroll 1
    for (int j = 0; j < 8; ++j) {
        int lr = wvid * 8 + j;
        int row = rbase + lr;
        float a1 = 0.f, a2 = 0.f;
        if (row < NN) {
            int n1 = cnt1[row]; if (n1 > SLOTS) n1 = SLOTS;
            int n2 = cnt2[row]; if (n2 > SLOTS) n2 = SLOTS;
            spmm_row2(buf1 + (size_t)row * SLOTS, n1, xb,
                      buf2 + (size_t)row * SLOTS, n2, xb, lane, a1, a2);
            s2b[(size_t)row * 64 + lane] = f2bf(a2);
        }
        sm1[lr * 64 + (lane ^ ((lr & 7) << 3))] = f2bf(a1);
    }
    __syncthreads();

    const int klo = (lane >> 4) * 8;
    const int r0 = lane & 15;
    const int r1 = r0 + 16;
    bf16x8 af00 = *(const bf16x8*)&sm1[r0 * 64 + (klo ^ ((r0 & 7) << 3))];
    bf16x8 af01 = *(const bf16x8*)&sm1[r0 * 64 + ((32 + klo) ^ ((r0 & 7) << 3))];
    bf16x8 af10 = *(const bf16x8*)&sm1[r1 * 64 + (klo ^ ((r1 & 7) << 3))];
    bf16x8 af11 = *(const bf16x8*)&sm1[r1 * 64 + ((32 + klo) ^ ((r1 & 7) << 3))];
    const bf16x8* wvp = (const bf16x8*)Wf1;
    const int row0 = rbase + r0;
    const int cq = (lane >> 4) * 4;
    for (int ct = wvid; ct < 125; ct += 4) {
        bf16x8 w0 = wvp[ct * 64 + lane];
        bf16x8 w1 = wvp[(125 + ct) * 64 + lane];
        f32x4 accA = {}, accB = {};
        accA = __builtin_amdgcn_mfma_f32_16x16x32_bf16(w0, af00, accA, 0, 0, 0);
        accA = __builtin_amdgcn_mfma_f32_16x16x32_bf16(w1, af01, accA, 0, 0, 0);
        accB = __builtin_amdgcn_mfma_f32_16x16x32_bf16(w0, af10, accB, 0, 0, 0);
        accB = __builtin_amdgcn_mfma_f32_16x16x32_bf16(w1, af11, accB, 0, 0, 0);
        int colbase = ct * 16 + cq;   // < 2000 always
        if (row0 < NN)      *(f32x4*)&C1[(size_t)row0 * 2000 + colbase] = accA;
        if (row0 + 16 < NN) *(f32x4*)&C1[(size_t)(row0 + 16) * 2000 + colbase] = accB;
    }
}

// ============ set-2 decoder GEMM (M2, from s2b) ============
__device__ __forceinline__ void dec_item(
    const ushort* __restrict__ S, const ushort* __restrict__ Wf, float* __restrict__ C,
    int Nc, int nct, int item, int lane) {
    const int M = NN;
    const int klo = (lane >> 4) * 8;
    int r0 = item * 32 + (lane & 15);
    int r1 = r0 + 16;
    const ushort* sp0 = S + (size_t)(r0 < M ? r0 : M - 1) * 64;
    const ushort* sp1 = S + (size_t)(r1 < M ? r1 : M - 1) * 64;
    bf16x8 af00 = *(const bf16x8*)(sp0 + klo);
    bf16x8 af01 = *(const bf16x8*)(sp0 + 32 + klo);
    bf16x8 af10 = *(const bf16x8*)(sp1 + klo);
    bf16x8 af11 = *(const bf16x8*)(sp1 + 32 + klo);
    const bf16x8* wv = (const bf16x8*)Wf;
    const int row0 = item * 32 + (lane & 15);
    const int cq = (lane >> 4) * 4;
    #pragma unroll 2
    for (int ct = 0; ct < nct; ++ct) {
        bf16x8 w0 = wv[ct * 64 + lane];
        bf16x8 w1 = wv[(nct + ct) * 64 + lane];
        f32x4 acc0 = {}, acc1 = {};
        acc0 = __builtin_amdgcn_mfma_f32_16x16x32_bf16(w0, af00, acc0, 0, 0, 0);
        acc0 = __builtin_amdgcn_mfma_f32_16x16x32_bf16(w1, af01, acc0, 0, 0, 0);
        acc1 = __builtin_amdgcn_mfma_f32_16x16x32_bf16(w0, af10, acc1, 0, 0, 0);
        acc1 = __builtin_amdgcn_mfma_f32_16x16x32_bf16(w1, af11, acc1, 0, 0, 0);
        int colbase = ct * 16 + cq;
        if (colbase + 3 < Nc) {
            if (row0 < M)      *(f32x4*)&C[(size_t)row0 * Nc + colbase] = acc0;
            if (row0 + 16 < M) *(f32x4*)&C[(size_t)(row0 + 16) * Nc + colbase] = acc1;
        }
    }
}

__global__ __launch_bounds__(256) void gemm_d2(
    const ushort* __restrict__ s2b, const ushort* __restrict__ Wf2, float* __restrict__ C2) {
    int item = blockIdx.x * 4 + (threadIdx.x >> 6);
    if (item < IPSET) dec_item(s2b, Wf2, C2, 500, 32, item, threadIdx.x & 63);
}

extern "C" void kernel_launch(void* const* d_in, const int* in_sizes, int n_in,
                              void* d_out, int out_size, void* d_ws, size_t ws_size,
                              hipStream_t stream) {
    const float* omics1 = (const float*)d_in[0];
    const float* omics2 = (const float*)d_in[1];
    const int*   ei1    = (const int*)d_in[2];
    const float* ew1    = (const float*)d_in[3];
    const int*   ei2    = (const int*)d_in[4];
    const float* ew2    = (const float*)d_in[5];
    const float* Wenc1  = (const float*)d_in[6];
    const float* Wenc2  = (const float*)d_in[7];
    const float* womega = (const float*)d_in[8];
    const float* uomega = (const float*)d_in[9];
    const float* Wdec1  = (const float*)d_in[10];
    const float* Wdec2  = (const float*)d_in[11];

    float* out  = (float*)d_out;
    float* e1   = out;
    float* e2   = e1 + (size_t)NN * 64;
    float* emb  = e2 + (size_t)NN * 64;
    float* alph = emb + (size_t)NN * 64;
    float* d1   = alph + (size_t)NN * 2;
    float* d2   = d1 + (size_t)NN * 2000;

    // edge buckets live in the d2 output region (100 MB >= 51.2 MB; 8B-aligned).
    // d2 is written ONLY by gemm_d2, the last kernel, after all bucket reads.
    // fused_dec1 writes d1 + s2b only -> no overlap with live buckets.
    int2* buf1 = (int2*)d2;
    int2* buf2 = buf1 + (size_t)NN * SLOTS;

    const int nBf1 = 63 * 4 * 64;    // Wenc1: K=2000 -> ng 63, nct 4
    const int nBf2 = 16 * 4 * 64;    // Wenc2: K=500  -> ng 16
    const int nWf1 = 2 * 125 * 64;   // Wdec1: Nc=2000 -> nct 125
    const int nWf2 = 2 * 32 * 64;    // Wdec2: Nc=500 -> nct 32

    char* w = (char*)d_ws;
    ushort* h1b = (ushort*)w;              w += (size_t)NN * 64 * 2;
    ushort* h2b = (ushort*)w;              w += (size_t)NN * 64 * 2;
    ushort* embb = (ushort*)w;             w += (size_t)NN * 64 * 2;
    ushort* s2b = (ushort*)w;              w += (size_t)NN * 64 * 2;
    int*   cnt1 = (int*)w;                 w += (size_t)NN * 4;
    int*   cnt2 = (int*)w;                 w += (size_t)NN * 4;
    ushort* Bf1 = (ushort*)w;              w += (size_t)nBf1 * 8 * 2;
    ushort* Bf2 = (ushort*)w;              w += (size_t)nBf2 * 8 * 2;
    ushort* Wf1 = (ushort*)w;              w += (size_t)nWf1 * 8 * 2;
    ushort* Wf2 = (ushort*)w;              w += (size_t)nWf2 * 8 * 2;

    dim3 b256(256);

    // ---- 1: fragments + cnt zeroing ----
    const int nz = 2 * NN;
    const int nfrag = nBf1 + nBf2 + nWf1 + nWf2 + nz;
    frag_zero<<<dim3((nfrag + 255) / 256), b256, 0, stream>>>(
        Wenc1, Bf1, 2000, 64, nBf1,
        Wenc2, Bf2, 500, 64, nBf2,
        Wdec1, Wf1, 64, 2000, nWf1,
        Wdec2, Wf2, 64, 500, nWf2,
        cnt1, nz);

    // ---- 2: bucket scatter || full encoder GEMM ----
    const int NSB = 512;
    k1_bucket_enc<<<dim3(NSB + (NITEMS + 3) / 4), b256, 0, stream>>>(
        ei1, ei1 + NE, ew1, cnt1, buf1,
        ei2, ei2 + NE, ew2, cnt2, buf2, NSB,
        omics1, Bf1, h1b, 2000, omics2, Bf2, h2b, 500);

    // ---- 3: fused encoder-spmm + attention ----
    spmm_attn<<<dim3((NN + 3) / 4), b256, 0, stream>>>(
        cnt1, buf1, h1b, cnt2, buf2, h2b, womega, uomega, e1, e2, emb, embb, alph);

    // ---- 4: fused decoder spmm + set-1 GEMM (writes d1, s2b) ----
    fused_dec1<<<dim3(IPSET), b256, 0, stream>>>(
        cnt1, buf1, cnt2, buf2, embb, s2b, Wf1, d1);

    // ---- 5: set-2 decoder GEMM (overwrites d2, incl. dead bucket region) ----
    gemm_d2<<<dim3((IPSET + 3) / 4), b256, 0, stream>>>(s2b, Wf2, d2);
}

// Round 13
// 569.664 us; speedup vs baseline: 1.0773x; 1.0773x over previous
//
#include <hip/hip_runtime.h>
#include <math.h>

#define NN 50000
#define NE 800000
#define IPSET 1563          // M2 items per set (ceil(50000/32))
#define NITEMS (2 * IPSET)  // enc/dec work items
#define SLOTS 64            // bucket capacity per row (Poisson(16): P(>=64) ~ 1e-18)

typedef __attribute__((ext_vector_type(8))) short bf16x8;
typedef __attribute__((ext_vector_type(4))) float f32x4;

__device__ __forceinline__ ushort f2bf(float f) {
    union { float f; unsigned u; } v; v.f = f;
    unsigned r = v.u + 0x7FFFu + ((v.u >> 16) & 1u);   // RNE
    return (ushort)(r >> 16);
}

__device__ __forceinline__ float bf2f(ushort u) {
    union { unsigned u; float f; } v; v.u = ((unsigned)u) << 16;
    return v.f;
}

// packed bf16 convert: 1 VALU inst per 2 floats (no builtin on gfx950 -> inline asm)
__device__ __forceinline__ unsigned cvtpk(float lo, float hi) {
    unsigned r;
    asm("v_cvt_pk_bf16_f32 %0, %1, %2" : "=v"(r) : "v"(lo), "v"(hi));
    return r;
}

__device__ __forceinline__ bf16x8 cvt8pk(const float* v) {
    union { unsigned u[4]; bf16x8 b; } o;
    o.u[0] = cvtpk(v[0], v[1]);
    o.u[1] = cvtpk(v[2], v[3]);
    o.u[2] = cvtpk(v[4], v[5]);
    o.u[3] = cvtpk(v[6], v[7]);
    return o.b;
}

// ============ fragment precompute + cnt zero (one launch) ============
__device__ __forceinline__ void frag_one(const float* __restrict__ src, ushort* __restrict__ dst,
                                         int K, int Nc, int t) {
    int nct = (Nc + 15) >> 4;
    int lane = t & 63, rest = t >> 6;
    int ct = rest % nct, g = rest / nct;
    int col = ct * 16 + (lane & 15);
    int kb = g * 32 + (lane >> 4) * 8;
    ushort u[8];
    #pragma unroll
    for (int j = 0; j < 8; ++j) {
        int k = kb + j;
        float v = (k < K && col < Nc) ? src[(size_t)k * Nc + col] : 0.f;
        u[j] = f2bf(v);
    }
    *(bf16x8*)&dst[(size_t)t * 8] = *(bf16x8*)u;
}

__global__ __launch_bounds__(256) void frag_zero(
    const float* __restrict__ s0, ushort* __restrict__ d0, int K0, int N0, int n0,
    const float* __restrict__ s1, ushort* __restrict__ d1, int K1, int N1, int n1,
    const float* __restrict__ s2, ushort* __restrict__ d2, int K2, int N2, int n2,
    const float* __restrict__ s3, ushort* __restrict__ d3, int K3, int N3, int n3,
    int* __restrict__ zbuf, int nz) {
    int t = blockIdx.x * 256 + threadIdx.x;
    if (t < n0) { frag_one(s0, d0, K0, N0, t); return; } t -= n0;
    if (t < n1) { frag_one(s1, d1, K1, N1, t); return; } t -= n1;
    if (t < n2) { frag_one(s2, d2, K2, N2, t); return; } t -= n2;
    if (t < n3) { frag_one(s3, d3, K3, N3, t); return; } t -= n3;
    if (t < nz) zbuf[t] = 0;
}

// ============ encoder GEMM item (M2; cvt_pk staging + C-write) ============
__device__ __forceinline__ void enc_item(
    const float* __restrict__ A, const ushort* __restrict__ Bf, ushort* __restrict__ C,
    int K, int item, int lane) {
    const int M = NN;
    const int klo = (lane >> 4) * 8;
    int r0 = item * 32 + (lane & 15);
    int r1 = r0 + 16;
    const float* ap0 = A + (size_t)(r0 < M ? r0 : M - 1) * K;
    const float* ap1 = A + (size_t)(r1 < M ? r1 : M - 1) * K;
    const bf16x8* bv = (const bf16x8*)Bf;
    const int ng = (K + 31) >> 5;
    f32x4 acc[2][4] = {};
    #pragma unroll 2
    for (int g = 0; g < ng; ++g) {
        int kg = g * 32 + klo;
        bf16x8 af[2];
        #pragma unroll
        for (int tt = 0; tt < 2; ++tt) {
            const float* ap = tt ? ap1 : ap0;
            float v[8];
            if (kg + 7 < K) {
                f32x4 a = *(const f32x4*)(ap + kg);
                f32x4 b = *(const f32x4*)(ap + kg + 4);
                v[0] = a.x; v[1] = a.y; v[2] = a.z; v[3] = a.w;
                v[4] = b.x; v[5] = b.y; v[6] = b.z; v[7] = b.w;
            } else {
                #pragma unroll
                for (int j = 0; j < 8; ++j) v[j] = (kg + j < K) ? ap[kg + j] : 0.f;
            }
            af[tt] = cvt8pk(v);
        }
        #pragma unroll
        for (int ct = 0; ct < 4; ++ct) {
            bf16x8 b = bv[(g * 4 + ct) * 64 + lane];
            acc[0][ct] = __builtin_amdgcn_mfma_f32_16x16x32_bf16(b, af[0], acc[0][ct], 0, 0, 0);
            acc[1][ct] = __builtin_amdgcn_mfma_f32_16x16x32_bf16(b, af[1], acc[1][ct], 0, 0, 0);
        }
    }
    const int cq = (lane >> 4) * 4;
    #pragma unroll
    for (int tt = 0; tt < 2; ++tt) {
        int row = item * 32 + tt * 16 + (lane & 15);
        if (row < M) {
            #pragma unroll
            for (int ct = 0; ct < 4; ++ct) {
                uint2 uu;
                uu.x = cvtpk(acc[tt][ct][0], acc[tt][ct][1]);
                uu.y = cvtpk(acc[tt][ct][2], acc[tt][ct][3]);
                *(uint2*)&C[(size_t)row * 64 + ct * 16 + cq] = uu;
            }
        }
    }
}

// ============ K1: bucket scatter (grid-stride) || ALL enc items ============
__global__ __launch_bounds__(256) void k1_bucket_enc(
    const int* __restrict__ r1, const int* __restrict__ ce1, const float* __restrict__ w1,
    int* __restrict__ cnt1, int2* __restrict__ buf1,
    const int* __restrict__ r2, const int* __restrict__ ce2, const float* __restrict__ w2,
    int* __restrict__ cnt2, int2* __restrict__ buf2, int nsb,
    const float* __restrict__ A1, const ushort* __restrict__ Bf1, ushort* __restrict__ C1, int K1,
    const float* __restrict__ A2, const ushort* __restrict__ Bf2, ushort* __restrict__ C2, int K2) {
    if ((int)blockIdx.x < nsb) {
        int stride = nsb * 256;
        for (int i = blockIdx.x * 256 + threadIdx.x; i < 2 * NE; i += stride) {
            if (i < NE) {
                int r = r1[i];
                int s = atomicAdd(&cnt1[r], 1);
                if (s < SLOTS) buf1[(size_t)r * SLOTS + s] = make_int2(ce1[i], __float_as_int(w1[i]));
            } else {
                int j = i - NE;
                int r = r2[j];
                int s = atomicAdd(&cnt2[r], 1);
                if (s < SLOTS) buf2[(size_t)r * SLOTS + s] = make_int2(ce2[j], __float_as_int(w2[j]));
            }
        }
        return;
    }
    int item = (blockIdx.x - nsb) * 4 + (threadIdx.x >> 6);
    if (item < NITEMS) {
        int lane = threadIdx.x & 63;
        if (item < IPSET) enc_item(A1, Bf1, C1, K1, item, lane);
        else              enc_item(A2, Bf2, C2, K2, item - IPSET, lane);
    }
}

// ============ dual-cursor interleaved spmm gather (bucket layout) ============
__device__ __forceinline__ void spmm_row2(
    const int2* __restrict__ p1, int n1, const ushort* __restrict__ x1,
    const int2* __restrict__ p2, int n2, const ushort* __restrict__ x2,
    int lane, float& acc1o, float& acc2o) {
    float acc1 = 0.f, acc2 = 0.f;
    int i1 = 0, i2 = 0;
    while (i1 + 3 < n1 && i2 + 3 < n2) {
        int2 a0 = p1[i1], a1 = p1[i1 + 1], a2 = p1[i1 + 2], a3 = p1[i1 + 3];
        int2 b0 = p2[i2], b1 = p2[i2 + 1], b2 = p2[i2 + 2], b3 = p2[i2 + 3];
        float ga0 = bf2f(x1[(size_t)a0.x * 64 + lane]);
        float gb0 = bf2f(x2[(size_t)b0.x * 64 + lane]);
        float ga1 = bf2f(x1[(size_t)a1.x * 64 + lane]);
        float gb1 = bf2f(x2[(size_t)b1.x * 64 + lane]);
        float ga2 = bf2f(x1[(size_t)a2.x * 64 + lane]);
        float gb2 = bf2f(x2[(size_t)b2.x * 64 + lane]);
        float ga3 = bf2f(x1[(size_t)a3.x * 64 + lane]);
        float gb3 = bf2f(x2[(size_t)b3.x * 64 + lane]);
        acc1 += __int_as_float(a0.y) * ga0; acc2 += __int_as_float(b0.y) * gb0;
        acc1 += __int_as_float(a1.y) * ga1; acc2 += __int_as_float(b1.y) * gb1;
        acc1 += __int_as_float(a2.y) * ga2; acc2 += __int_as_float(b2.y) * gb2;
        acc1 += __int_as_float(a3.y) * ga3; acc2 += __int_as_float(b3.y) * gb3;
        i1 += 4; i2 += 4;
    }
    for (; i1 + 3 < n1; i1 += 4) {
        int2 a0 = p1[i1], a1 = p1[i1 + 1], a2 = p1[i1 + 2], a3 = p1[i1 + 3];
        float g0 = bf2f(x1[(size_t)a0.x * 64 + lane]);
        float g1 = bf2f(x1[(size_t)a1.x * 64 + lane]);
        float g2 = bf2f(x1[(size_t)a2.x * 64 + lane]);
        float g3 = bf2f(x1[(size_t)a3.x * 64 + lane]);
        acc1 += __int_as_float(a0.y) * g0; acc1 += __int_as_float(a1.y) * g1;
        acc1 += __int_as_float(a2.y) * g2; acc1 += __int_as_float(a3.y) * g3;
    }
    for (; i2 + 3 < n2; i2 += 4) {
        int2 b0 = p2[i2], b1 = p2[i2 + 1], b2 = p2[i2 + 2], b3 = p2[i2 + 3];
        float g0 = bf2f(x2[(size_t)b0.x * 64 + lane]);
        float g1 = bf2f(x2[(size_t)b1.x * 64 + lane]);
        float g2 = bf2f(x2[(size_t)b2.x * 64 + lane]);
        float g3 = bf2f(x2[(size_t)b3.x * 64 + lane]);
        acc2 += __int_as_float(b0.y) * g0; acc2 += __int_as_float(b1.y) * g1;
        acc2 += __int_as_float(b2.y) * g2; acc2 += __int_as_float(b3.y) * g3;
    }
    for (; i1 < n1; ++i1) {
        int2 p = p1[i1];
        acc1 += __int_as_float(p.y) * bf2f(x1[(size_t)p.x * 64 + lane]);
    }
    for (; i2 < n2; ++i2) {
        int2 p = p2[i2];
        acc2 += __int_as_float(p.y) * bf2f(x2[(size_t)p.x * 64 + lane]);
    }
    acc1o = acc1; acc2o = acc2;
}

// ============ fused encoder-spmm + attention, wave per node ============
__global__ __launch_bounds__(256) void spmm_attn(
    const int* __restrict__ cnt1, const int2* __restrict__ buf1, const ushort* __restrict__ x1,
    const int* __restrict__ cnt2, const int2* __restrict__ buf2, const ushort* __restrict__ x2,
    const float* __restrict__ Wo, const float* __restrict__ uo,
    float* __restrict__ e1, float* __restrict__ e2,
    float* __restrict__ emb, ushort* __restrict__ embb, float* __restrict__ alpha) {
    const int lane = threadIdx.x & 63;
    const int node = (blockIdx.x * 256 + threadIdx.x) >> 6;
    if (node >= NN) return;

    int n1 = cnt1[node]; if (n1 > SLOTS) n1 = SLOTS;
    int n2 = cnt2[node]; if (n2 > SLOTS) n2 = SLOTS;
    float ev0, ev1;
    spmm_row2(buf1 + (size_t)node * SLOTS, n1, x1,
              buf2 + (size_t)node * SLOTS, n2, x2, lane, ev0, ev1);

    float acc1 = 0.f, acc2 = 0.f;
    #pragma unroll 8
    for (int k = 0; k < 64; ++k) {
        float wv = Wo[k * 64 + lane];
        acc1 = fmaf(__shfl(ev0, k), wv, acc1);
        acc2 = fmaf(__shfl(ev1, k), wv, acc2);
    }
    float u = uo[lane];
    float t1 = tanhf(acc1) * u;
    float t2 = tanhf(acc2) * u;
    #pragma unroll
    for (int off = 32; off; off >>= 1) {
        t1 += __shfl_xor(t1, off);
        t2 += __shfl_xor(t2, off);
    }
    float m = fmaxf(t1, t2);
    float a1 = expf(t1 - m), a2 = expf(t2 - m);
    float sden = a1 + a2;
    a1 /= sden; a2 /= sden;

    const size_t base = (size_t)node * 64;
    float ec = a1 * ev0 + a2 * ev1;
    e1[base + lane] = ev0;
    e2[base + lane] = ev1;
    emb[base + lane] = ec;
    embb[base + lane] = f2bf(ec);
    if (lane == 0) *(float2*)&alpha[(size_t)node * 2] = make_float2(a1, a2);
}

// ============ decoder spmm: wave handles node r for BOTH sets ============
__global__ __launch_bounds__(256) void spmm_dec(
    const int* __restrict__ cnt1, const int2* __restrict__ buf1,
    const int* __restrict__ cnt2, const int2* __restrict__ buf2,
    const ushort* __restrict__ xb, ushort* __restrict__ s1b, ushort* __restrict__ s2b) {
    const int lane = threadIdx.x & 63;
    const int row = (blockIdx.x * 256 + threadIdx.x) >> 6;
    if (row >= NN) return;
    int n1 = cnt1[row]; if (n1 > SLOTS) n1 = SLOTS;
    int n2 = cnt2[row]; if (n2 > SLOTS) n2 = SLOTS;
    float acc1, acc2;
    spmm_row2(buf1 + (size_t)row * SLOTS, n1, xb,
              buf2 + (size_t)row * SLOTS, n2, xb, lane, acc1, acc2);
    s1b[(size_t)row * 64 + lane] = f2bf(acc1);
    s2b[(size_t)row * 64 + lane] = f2bf(acc2);
}

// ============ decoder GEMM (M2: 2 row-tiles, shared W-frag loads) ============
__device__ __forceinline__ void dec_item(
    const ushort* __restrict__ S, const ushort* __restrict__ Wf, float* __restrict__ C,
    int Nc, int nct, int item, int lane) {
    const int M = NN;
    const int klo = (lane >> 4) * 8;
    int r0 = item * 32 + (lane & 15);
    int r1 = r0 + 16;
    const ushort* sp0 = S + (size_t)(r0 < M ? r0 : M - 1) * 64;
    const ushort* sp1 = S + (size_t)(r1 < M ? r1 : M - 1) * 64;
    bf16x8 af00 = *(const bf16x8*)(sp0 + klo);
    bf16x8 af01 = *(const bf16x8*)(sp0 + 32 + klo);
    bf16x8 af10 = *(const bf16x8*)(sp1 + klo);
    bf16x8 af11 = *(const bf16x8*)(sp1 + 32 + klo);
    const bf16x8* wv = (const bf16x8*)Wf;
    const int row0 = item * 32 + (lane & 15);
    const int cq = (lane >> 4) * 4;
    #pragma unroll 2
    for (int ct = 0; ct < nct; ++ct) {
        bf16x8 w0 = wv[ct * 64 + lane];
        bf16x8 w1 = wv[(nct + ct) * 64 + lane];
        f32x4 acc0 = {}, acc1 = {};
        acc0 = __builtin_amdgcn_mfma_f32_16x16x32_bf16(w0, af00, acc0, 0, 0, 0);
        acc0 = __builtin_amdgcn_mfma_f32_16x16x32_bf16(w1, af01, acc0, 0, 0, 0);
        acc1 = __builtin_amdgcn_mfma_f32_16x16x32_bf16(w0, af10, acc1, 0, 0, 0);
        acc1 = __builtin_amdgcn_mfma_f32_16x16x32_bf16(w1, af11, acc1, 0, 0, 0);
        int colbase = ct * 16 + cq;
        if (colbase + 3 < Nc) {
            if (row0 < M)      *(f32x4*)&C[(size_t)row0 * Nc + colbase] = acc0;
            if (row0 + 16 < M) *(f32x4*)&C[(size_t)(row0 + 16) * Nc + colbase] = acc1;
        }
    }
}

__global__ __launch_bounds__(256) void gemm_dec4(
    const ushort* __restrict__ S1, const ushort* __restrict__ Wf1, float* __restrict__ C1, int Nc1, int nct1,
    const ushort* __restrict__ S2, const ushort* __restrict__ Wf2, float* __restrict__ C2, int Nc2, int nct2) {
    int item = blockIdx.x * 4 + (threadIdx.x >> 6);
    if (item >= NITEMS) return;
    const int lane = threadIdx.x & 63;
    if (item < IPSET) dec_item(S1, Wf1, C1, Nc1, nct1, item, lane);
    else              dec_item(S2, Wf2, C2, Nc2, nct2, item - IPSET, lane);
}

extern "C" void kernel_launch(void* const* d_in, const int* in_sizes, int n_in,
                              void* d_out, int out_size, void* d_ws, size_t ws_size,
                              hipStream_t stream) {
    const float* omics1 = (const float*)d_in[0];
    const float* omics2 = (const float*)d_in[1];
    const int*   ei1    = (const int*)d_in[2];
    const float* ew1    = (const float*)d_in[3];
    const int*   ei2    = (const int*)d_in[4];
    const float* ew2    = (const float*)d_in[5];
    const float* Wenc1  = (const float*)d_in[6];
    const float* Wenc2  = (const float*)d_in[7];
    const float* womega = (const float*)d_in[8];
    const float* uomega = (const float*)d_in[9];
    const float* Wdec1  = (const float*)d_in[10];
    const float* Wdec2  = (const float*)d_in[11];

    float* out  = (float*)d_out;
    float* e1   = out;
    float* e2   = e1 + (size_t)NN * 64;
    float* emb  = e2 + (size_t)NN * 64;
    float* alph = emb + (size_t)NN * 64;
    float* d1   = alph + (size_t)NN * 2;
    float* d2   = d1 + (size_t)NN * 2000;

    // edge buckets live in the d1 output region (free scratch until gemm_dec4 writes it).
    // d1 = 400 MB >= 2 * 25.6 MB; 8B-aligned.
    int2* buf1 = (int2*)d1;
    int2* buf2 = buf1 + (size_t)NN * SLOTS;

    const int nBf1 = 63 * 4 * 64;    // Wenc1: K=2000 -> ng 63, nct 4
    const int nBf2 = 16 * 4 * 64;    // Wenc2: K=500  -> ng 16
    const int nWf1 = 2 * 125 * 64;   // Wdec1: Nc=2000 -> nct 125
    const int nWf2 = 2 * 32 * 64;    // Wdec2: Nc=500 -> nct 32

    char* w = (char*)d_ws;
    ushort* h1b = (ushort*)w;              w += (size_t)NN * 64 * 2;
    ushort* h2b = (ushort*)w;              w += (size_t)NN * 64 * 2;
    ushort* embb = (ushort*)w;             w += (size_t)NN * 64 * 2;
    ushort* s1b = (ushort*)w;              w += (size_t)NN * 64 * 2;
    ushort* s2b = (ushort*)w;              w += (size_t)NN * 64 * 2;
    int*   cnt1 = (int*)w;                 w += (size_t)NN * 4;
    int*   cnt2 = (int*)w;                 w += (size_t)NN * 4;
    ushort* Bf1 = (ushort*)w;              w += (size_t)nBf1 * 8 * 2;
    ushort* Bf2 = (ushort*)w;              w += (size_t)nBf2 * 8 * 2;
    ushort* Wf1 = (ushort*)w;              w += (size_t)nWf1 * 8 * 2;
    ushort* Wf2 = (ushort*)w;              w += (size_t)nWf2 * 8 * 2;

    dim3 b256(256);

    // ---- 1: fragments + cnt zeroing ----
    const int nz = 2 * NN;
    const int nfrag = nBf1 + nBf2 + nWf1 + nWf2 + nz;
    frag_zero<<<dim3((nfrag + 255) / 256), b256, 0, stream>>>(
        Wenc1, Bf1, 2000, 64, nBf1,
        Wenc2, Bf2, 500, 64, nBf2,
        Wdec1, Wf1, 64, 2000, nWf1,
        Wdec2, Wf2, 64, 500, nWf2,
        cnt1, nz);

    // ---- 2: bucket scatter || full encoder GEMM ----
    const int NSB = 512;
    k1_bucket_enc<<<dim3(NSB + (NITEMS + 3) / 4), b256, 0, stream>>>(
        ei1, ei1 + NE, ew1, cnt1, buf1,
        ei2, ei2 + NE, ew2, cnt2, buf2, NSB,
        omics1, Bf1, h1b, 2000, omics2, Bf2, h2b, 500);

    // ---- 3: fused encoder-spmm + attention ----
    spmm_attn<<<dim3((NN + 3) / 4), b256, 0, stream>>>(
        cnt1, buf1, h1b, cnt2, buf2, h2b, womega, uomega, e1, e2, emb, embb, alph);

    // ---- 4: decoder spmm ----
    spmm_dec<<<dim3((NN + 3) / 4), b256, 0, stream>>>(
        cnt1, buf1, cnt2, buf2, embb, s1b, s2b);

    // ---- 5: decoder GEMMs (overwrites d1/d2, incl. dead bucket region) ----
    gemm_dec4<<<dim3((NITEMS + 3) / 4), b256, 0, stream>>>(
        s1b, Wf1, d1, 2000, 125, s2b, Wf2, d2, 500, 32);
}

// Round 14
// 562.359 us; speedup vs baseline: 1.0913x; 1.0130x over previous
//
#include <hip/hip_runtime.h>
#include <math.h>

#define NN 50000
#define NE 800000
#define IPSET 1563          // M2 items per set (ceil(50000/32))
#define NITEMS (2 * IPSET)  // enc/dec work items
#define SLOTS 64            // bucket capacity per row (Poisson(16): P(>=64) ~ 1e-18)

typedef __attribute__((ext_vector_type(8))) short bf16x8;
typedef __attribute__((ext_vector_type(4))) float f32x4;

__device__ __forceinline__ ushort f2bf(float f) {
    union { float f; unsigned u; } v; v.f = f;
    unsigned r = v.u + 0x7FFFu + ((v.u >> 16) & 1u);   // RNE
    return (ushort)(r >> 16);
}

__device__ __forceinline__ float bf2f(ushort u) {
    union { unsigned u; float f; } v; v.u = ((unsigned)u) << 16;
    return v.f;
}

// packed bf16 convert: 1 VALU inst per 2 floats (no builtin on gfx950 -> inline asm)
__device__ __forceinline__ unsigned cvtpk(float lo, float hi) {
    unsigned r;
    asm("v_cvt_pk_bf16_f32 %0, %1, %2" : "=v"(r) : "v"(lo), "v"(hi));
    return r;
}

__device__ __forceinline__ bf16x8 cvt8pk(const float* v) {
    union { unsigned u[4]; bf16x8 b; } o;
    o.u[0] = cvtpk(v[0], v[1]);
    o.u[1] = cvtpk(v[2], v[3]);
    o.u[2] = cvtpk(v[4], v[5]);
    o.u[3] = cvtpk(v[6], v[7]);
    return o.b;
}

// 4B edge payload: lo16 = col (NN < 65536), hi16 = bf16 weight bits
__device__ __forceinline__ unsigned pack_edge(int col, float w) {
    return (unsigned)col | ((unsigned)f2bf(w) << 16);
}
__device__ __forceinline__ int   pcol(unsigned p) { return (int)(p & 0xFFFFu); }
__device__ __forceinline__ float pwt(unsigned p)  { return __int_as_float(p & 0xFFFF0000u); }

// ============ fragment precompute + cnt zero (one launch) ============
__device__ __forceinline__ void frag_one(const float* __restrict__ src, ushort* __restrict__ dst,
                                         int K, int Nc, int t) {
    int nct = (Nc + 15) >> 4;
    int lane = t & 63, rest = t >> 6;
    int ct = rest % nct, g = rest / nct;
    int col = ct * 16 + (lane & 15);
    int kb = g * 32 + (lane >> 4) * 8;
    ushort u[8];
    #pragma unroll
    for (int j = 0; j < 8; ++j) {
        int k = kb + j;
        float v = (k < K && col < Nc) ? src[(size_t)k * Nc + col] : 0.f;
        u[j] = f2bf(v);
    }
    *(bf16x8*)&dst[(size_t)t * 8] = *(bf16x8*)u;
}

__global__ __launch_bounds__(256) void frag_zero(
    const float* __restrict__ s0, ushort* __restrict__ d0, int K0, int N0, int n0,
    const float* __restrict__ s1, ushort* __restrict__ d1, int K1, int N1, int n1,
    const float* __restrict__ s2, ushort* __restrict__ d2, int K2, int N2, int n2,
    const float* __restrict__ s3, ushort* __restrict__ d3, int K3, int N3, int n3,
    int* __restrict__ zbuf, int nz) {
    int t = blockIdx.x * 256 + threadIdx.x;
    if (t < n0) { frag_one(s0, d0, K0, N0, t); return; } t -= n0;
    if (t < n1) { frag_one(s1, d1, K1, N1, t); return; } t -= n1;
    if (t < n2) { frag_one(s2, d2, K2, N2, t); return; } t -= n2;
    if (t < n3) { frag_one(s3, d3, K3, N3, t); return; } t -= n3;
    if (t < nz) zbuf[t] = 0;
}

// ============ encoder GEMM item (M2; cvt_pk staging + C-write) ============
__device__ __forceinline__ void enc_item(
    const float* __restrict__ A, const ushort* __restrict__ Bf, ushort* __restrict__ C,
    int K, int item, int lane) {
    const int M = NN;
    const int klo = (lane >> 4) * 8;
    int r0 = item * 32 + (lane & 15);
    int r1 = r0 + 16;
    const float* ap0 = A + (size_t)(r0 < M ? r0 : M - 1) * K;
    const float* ap1 = A + (size_t)(r1 < M ? r1 : M - 1) * K;
    const bf16x8* bv = (const bf16x8*)Bf;
    const int ng = (K + 31) >> 5;
    f32x4 acc[2][4] = {};
    #pragma unroll 2
    for (int g = 0; g < ng; ++g) {
        int kg = g * 32 + klo;
        bf16x8 af[2];
        #pragma unroll
        for (int tt = 0; tt < 2; ++tt) {
            const float* ap = tt ? ap1 : ap0;
            float v[8];
            if (kg + 7 < K) {
                f32x4 a = *(const f32x4*)(ap + kg);
                f32x4 b = *(const f32x4*)(ap + kg + 4);
                v[0] = a.x; v[1] = a.y; v[2] = a.z; v[3] = a.w;
                v[4] = b.x; v[5] = b.y; v[6] = b.z; v[7] = b.w;
            } else {
                #pragma unroll
                for (int j = 0; j < 8; ++j) v[j] = (kg + j < K) ? ap[kg + j] : 0.f;
            }
            af[tt] = cvt8pk(v);
        }
        #pragma unroll
        for (int ct = 0; ct < 4; ++ct) {
            bf16x8 b = bv[(g * 4 + ct) * 64 + lane];
            acc[0][ct] = __builtin_amdgcn_mfma_f32_16x16x32_bf16(b, af[0], acc[0][ct], 0, 0, 0);
            acc[1][ct] = __builtin_amdgcn_mfma_f32_16x16x32_bf16(b, af[1], acc[1][ct], 0, 0, 0);
        }
    }
    const int cq = (lane >> 4) * 4;
    #pragma unroll
    for (int tt = 0; tt < 2; ++tt) {
        int row = item * 32 + tt * 16 + (lane & 15);
        if (row < M) {
            #pragma unroll
            for (int ct = 0; ct < 4; ++ct) {
                uint2 uu;
                uu.x = cvtpk(acc[tt][ct][0], acc[tt][ct][1]);
                uu.y = cvtpk(acc[tt][ct][2], acc[tt][ct][3]);
                *(uint2*)&C[(size_t)row * 64 + ct * 16 + cq] = uu;
            }
        }
    }
}

// ============ K1: bucket scatter (grid-stride) || ALL enc items ============
__global__ __launch_bounds__(256) void k1_bucket_enc(
    const int* __restrict__ r1, const int* __restrict__ ce1, const float* __restrict__ w1,
    int* __restrict__ cnt1, unsigned* __restrict__ buf1,
    const int* __restrict__ r2, const int* __restrict__ ce2, const float* __restrict__ w2,
    int* __restrict__ cnt2, unsigned* __restrict__ buf2, int nsb,
    const float* __restrict__ A1, const ushort* __restrict__ Bf1, ushort* __restrict__ C1, int K1,
    const float* __restrict__ A2, const ushort* __restrict__ Bf2, ushort* __restrict__ C2, int K2) {
    if ((int)blockIdx.x < nsb) {
        int stride = nsb * 256;
        for (int i = blockIdx.x * 256 + threadIdx.x; i < 2 * NE; i += stride) {
            if (i < NE) {
                int r = r1[i];
                int s = atomicAdd(&cnt1[r], 1);
                if (s < SLOTS) buf1[(size_t)r * SLOTS + s] = pack_edge(ce1[i], w1[i]);
            } else {
                int j = i - NE;
                int r = r2[j];
                int s = atomicAdd(&cnt2[r], 1);
                if (s < SLOTS) buf2[(size_t)r * SLOTS + s] = pack_edge(ce2[j], w2[j]);
            }
        }
        return;
    }
    int item = (blockIdx.x - nsb) * 4 + (threadIdx.x >> 6);
    if (item < NITEMS) {
        int lane = threadIdx.x & 63;
        if (item < IPSET) enc_item(A1, Bf1, C1, K1, item, lane);
        else              enc_item(A2, Bf2, C2, K2, item - IPSET, lane);
    }
}

// ============ dual-cursor interleaved spmm gather (4B packed payload) ============
__device__ __forceinline__ void spmm_row2(
    const unsigned* __restrict__ p1, int n1, const ushort* __restrict__ x1,
    const unsigned* __restrict__ p2, int n2, const ushort* __restrict__ x2,
    int lane, float& acc1o, float& acc2o) {
    float acc1 = 0.f, acc2 = 0.f;
    int i1 = 0, i2 = 0;
    while (i1 + 3 < n1 && i2 + 3 < n2) {
        unsigned a0 = p1[i1], a1 = p1[i1 + 1], a2 = p1[i1 + 2], a3 = p1[i1 + 3];
        unsigned b0 = p2[i2], b1 = p2[i2 + 1], b2 = p2[i2 + 2], b3 = p2[i2 + 3];
        float ga0 = bf2f(x1[(size_t)pcol(a0) * 64 + lane]);
        float gb0 = bf2f(x2[(size_t)pcol(b0) * 64 + lane]);
        float ga1 = bf2f(x1[(size_t)pcol(a1) * 64 + lane]);
        float gb1 = bf2f(x2[(size_t)pcol(b1) * 64 + lane]);
        float ga2 = bf2f(x1[(size_t)pcol(a2) * 64 + lane]);
        float gb2 = bf2f(x2[(size_t)pcol(b2) * 64 + lane]);
        float ga3 = bf2f(x1[(size_t)pcol(a3) * 64 + lane]);
        float gb3 = bf2f(x2[(size_t)pcol(b3) * 64 + lane]);
        acc1 += pwt(a0) * ga0; acc2 += pwt(b0) * gb0;
        acc1 += pwt(a1) * ga1; acc2 += pwt(b1) * gb1;
        acc1 += pwt(a2) * ga2; acc2 += pwt(b2) * gb2;
        acc1 += pwt(a3) * ga3; acc2 += pwt(b3) * gb3;
        i1 += 4; i2 += 4;
    }
    for (; i1 + 3 < n1; i1 += 4) {
        unsigned a0 = p1[i1], a1 = p1[i1 + 1], a2 = p1[i1 + 2], a3 = p1[i1 + 3];
        float g0 = bf2f(x1[(size_t)pcol(a0) * 64 + lane]);
        float g1 = bf2f(x1[(size_t)pcol(a1) * 64 + lane]);
        float g2 = bf2f(x1[(size_t)pcol(a2) * 64 + lane]);
        float g3 = bf2f(x1[(size_t)pcol(a3) * 64 + lane]);
        acc1 += pwt(a0) * g0; acc1 += pwt(a1) * g1;
        acc1 += pwt(a2) * g2; acc1 += pwt(a3) * g3;
    }
    for (; i2 + 3 < n2; i2 += 4) {
        unsigned b0 = p2[i2], b1 = p2[i2 + 1], b2 = p2[i2 + 2], b3 = p2[i2 + 3];
        float g0 = bf2f(x2[(size_t)pcol(b0) * 64 + lane]);
        float g1 = bf2f(x2[(size_t)pcol(b1) * 64 + lane]);
        float g2 = bf2f(x2[(size_t)pcol(b2) * 64 + lane]);
        float g3 = bf2f(x2[(size_t)pcol(b3) * 64 + lane]);
        acc2 += pwt(b0) * g0; acc2 += pwt(b1) * g1;
        acc2 += pwt(b2) * g2; acc2 += pwt(b3) * g3;
    }
    for (; i1 < n1; ++i1) {
        unsigned p = p1[i1];
        acc1 += pwt(p) * bf2f(x1[(size_t)pcol(p) * 64 + lane]);
    }
    for (; i2 < n2; ++i2) {
        unsigned p = p2[i2];
        acc2 += pwt(p) * bf2f(x2[(size_t)pcol(p) * 64 + lane]);
    }
    acc1o = acc1; acc2o = acc2;
}

// ============ fused encoder-spmm + attention, wave per node ============
__global__ __launch_bounds__(256) void spmm_attn(
    const int* __restrict__ cnt1, const unsigned* __restrict__ buf1, const ushort* __restrict__ x1,
    const int* __restrict__ cnt2, const unsigned* __restrict__ buf2, const ushort* __restrict__ x2,
    const float* __restrict__ Wo, const float* __restrict__ uo,
    float* __restrict__ e1, float* __restrict__ e2,
    float* __restrict__ emb, ushort* __restrict__ embb, float* __restrict__ alpha) {
    const int lane = threadIdx.x & 63;
    const int node = (blockIdx.x * 256 + threadIdx.x) >> 6;
    if (node >= NN) return;

    int n1 = cnt1[node]; if (n1 > SLOTS) n1 = SLOTS;
    int n2 = cnt2[node]; if (n2 > SLOTS) n2 = SLOTS;
    float ev0, ev1;
    spmm_row2(buf1 + (size_t)node * SLOTS, n1, x1,
              buf2 + (size_t)node * SLOTS, n2, x2, lane, ev0, ev1);

    float acc1 = 0.f, acc2 = 0.f;
    #pragma unroll 8
    for (int k = 0; k < 64; ++k) {
        float wv = Wo[k * 64 + lane];
        acc1 = fmaf(__shfl(ev0, k), wv, acc1);
        acc2 = fmaf(__shfl(ev1, k), wv, acc2);
    }
    float u = uo[lane];
    float t1 = tanhf(acc1) * u;
    float t2 = tanhf(acc2) * u;
    #pragma unroll
    for (int off = 32; off; off >>= 1) {
        t1 += __shfl_xor(t1, off);
        t2 += __shfl_xor(t2, off);
    }
    float m = fmaxf(t1, t2);
    float a1 = expf(t1 - m), a2 = expf(t2 - m);
    float sden = a1 + a2;
    a1 /= sden; a2 /= sden;

    const size_t base = (size_t)node * 64;
    float ec = a1 * ev0 + a2 * ev1;
    e1[base + lane] = ev0;
    e2[base + lane] = ev1;
    emb[base + lane] = ec;
    embb[base + lane] = f2bf(ec);
    if (lane == 0) *(float2*)&alpha[(size_t)node * 2] = make_float2(a1, a2);
}

// ============ decoder spmm: wave handles node r for BOTH sets ============
__global__ __launch_bounds__(256) void spmm_dec(
    const int* __restrict__ cnt1, const unsigned* __restrict__ buf1,
    const int* __restrict__ cnt2, const unsigned* __restrict__ buf2,
    const ushort* __restrict__ xb, ushort* __restrict__ s1b, ushort* __restrict__ s2b) {
    const int lane = threadIdx.x & 63;
    const int row = (blockIdx.x * 256 + threadIdx.x) >> 6;
    if (row >= NN) return;
    int n1 = cnt1[row]; if (n1 > SLOTS) n1 = SLOTS;
    int n2 = cnt2[row]; if (n2 > SLOTS) n2 = SLOTS;
    float acc1, acc2;
    spmm_row2(buf1 + (size_t)row * SLOTS, n1, xb,
              buf2 + (size_t)row * SLOTS, n2, xb, lane, acc1, acc2);
    s1b[(size_t)row * 64 + lane] = f2bf(acc1);
    s2b[(size_t)row * 64 + lane] = f2bf(acc2);
}

// ============ decoder GEMM (M2: 2 row-tiles, shared W-frag loads) ============
__device__ __forceinline__ void dec_item(
    const ushort* __restrict__ S, const ushort* __restrict__ Wf, float* __restrict__ C,
    int Nc, int nct, int item, int lane) {
    const int M = NN;
    const int klo = (lane >> 4) * 8;
    int r0 = item * 32 + (lane & 15);
    int r1 = r0 + 16;
    const ushort* sp0 = S + (size_t)(r0 < M ? r0 : M - 1) * 64;
    const ushort* sp1 = S + (size_t)(r1 < M ? r1 : M - 1) * 64;
    bf16x8 af00 = *(const bf16x8*)(sp0 + klo);
    bf16x8 af01 = *(const bf16x8*)(sp0 + 32 + klo);
    bf16x8 af10 = *(const bf16x8*)(sp1 + klo);
    bf16x8 af11 = *(const bf16x8*)(sp1 + 32 + klo);
    const bf16x8* wv = (const bf16x8*)Wf;
    const int row0 = item * 32 + (lane & 15);
    const int cq = (lane >> 4) * 4;
    #pragma unroll 2
    for (int ct = 0; ct < nct; ++ct) {
        bf16x8 w0 = wv[ct * 64 + lane];
        bf16x8 w1 = wv[(nct + ct) * 64 + lane];
        f32x4 acc0 = {}, acc1 = {};
        acc0 = __builtin_amdgcn_mfma_f32_16x16x32_bf16(w0, af00, acc0, 0, 0, 0);
        acc0 = __builtin_amdgcn_mfma_f32_16x16x32_bf16(w1, af01, acc0, 0, 0, 0);
        acc1 = __builtin_amdgcn_mfma_f32_16x16x32_bf16(w0, af10, acc1, 0, 0, 0);
        acc1 = __builtin_amdgcn_mfma_f32_16x16x32_bf16(w1, af11, acc1, 0, 0, 0);
        int colbase = ct * 16 + cq;
        if (colbase + 3 < Nc) {
            if (row0 < M)      *(f32x4*)&C[(size_t)row0 * Nc + colbase] = acc0;
            if (row0 + 16 < M) *(f32x4*)&C[(size_t)(row0 + 16) * Nc + colbase] = acc1;
        }
    }
}

__global__ __launch_bounds__(256) void gemm_dec4(
    const ushort* __restrict__ S1, const ushort* __restrict__ Wf1, float* __restrict__ C1, int Nc1, int nct1,
    const ushort* __restrict__ S2, const ushort* __restrict__ Wf2, float* __restrict__ C2, int Nc2, int nct2) {
    int item = blockIdx.x * 4 + (threadIdx.x >> 6);
    if (item >= NITEMS) return;
    const int lane = threadIdx.x & 63;
    if (item < IPSET) dec_item(S1, Wf1, C1, Nc1, nct1, item, lane);
    else              dec_item(S2, Wf2, C2, Nc2, nct2, item - IPSET, lane);
}

extern "C" void kernel_launch(void* const* d_in, const int* in_sizes, int n_in,
                              void* d_out, int out_size, void* d_ws, size_t ws_size,
                              hipStream_t stream) {
    const float* omics1 = (const float*)d_in[0];
    const float* omics2 = (const float*)d_in[1];
    const int*   ei1    = (const int*)d_in[2];
    const float* ew1    = (const float*)d_in[3];
    const int*   ei2    = (const int*)d_in[4];
    const float* ew2    = (const float*)d_in[5];
    const float* Wenc1  = (const float*)d_in[6];
    const float* Wenc2  = (const float*)d_in[7];
    const float* womega = (const float*)d_in[8];
    const float* uomega = (const float*)d_in[9];
    const float* Wdec1  = (const float*)d_in[10];
    const float* Wdec2  = (const float*)d_in[11];

    float* out  = (float*)d_out;
    float* e1   = out;
    float* e2   = e1 + (size_t)NN * 64;
    float* emb  = e2 + (size_t)NN * 64;
    float* alph = emb + (size_t)NN * 64;
    float* d1   = alph + (size_t)NN * 2;
    float* d2   = d1 + (size_t)NN * 2000;

    // edge buckets live in the d1 output region (free scratch until gemm_dec4 writes it).
    // 2 * NN * 64 * 4B = 25.6 MB << 400 MB; 4B-aligned.
    unsigned* buf1 = (unsigned*)d1;
    unsigned* buf2 = buf1 + (size_t)NN * SLOTS;

    const int nBf1 = 63 * 4 * 64;    // Wenc1: K=2000 -> ng 63, nct 4
    const int nBf2 = 16 * 4 * 64;    // Wenc2: K=500  -> ng 16
    const int nWf1 = 2 * 125 * 64;   // Wdec1: Nc=2000 -> nct 125
    const int nWf2 = 2 * 32 * 64;    // Wdec2: Nc=500 -> nct 32

    char* w = (char*)d_ws;
    ushort* h1b = (ushort*)w;              w += (size_t)NN * 64 * 2;
    ushort* h2b = (ushort*)w;              w += (size_t)NN * 64 * 2;
    ushort* embb = (ushort*)w;             w += (size_t)NN * 64 * 2;
    ushort* s1b = (ushort*)w;              w += (size_t)NN * 64 * 2;
    ushort* s2b = (ushort*)w;              w += (size_t)NN * 64 * 2;
    int*   cnt1 = (int*)w;                 w += (size_t)NN * 4;
    int*   cnt2 = (int*)w;                 w += (size_t)NN * 4;
    ushort* Bf1 = (ushort*)w;              w += (size_t)nBf1 * 8 * 2;
    ushort* Bf2 = (ushort*)w;              w += (size_t)nBf2 * 8 * 2;
    ushort* Wf1 = (ushort*)w;              w += (size_t)nWf1 * 8 * 2;
    ushort* Wf2 = (ushort*)w;              w += (size_t)nWf2 * 8 * 2;

    dim3 b256(256);

    // ---- 1: fragments + cnt zeroing ----
    const int nz = 2 * NN;
    const int nfrag = nBf1 + nBf2 + nWf1 + nWf2 + nz;
    frag_zero<<<dim3((nfrag + 255) / 256), b256, 0, stream>>>(
        Wenc1, Bf1, 2000, 64, nBf1,
        Wenc2, Bf2, 500, 64, nBf2,
        Wdec1, Wf1, 64, 2000, nWf1,
        Wdec2, Wf2, 64, 500, nWf2,
        cnt1, nz);

    // ---- 2: bucket scatter || full encoder GEMM ----
    const int NSB = 512;
    k1_bucket_enc<<<dim3(NSB + (NITEMS + 3) / 4), b256, 0, stream>>>(
        ei1, ei1 + NE, ew1, cnt1, buf1,
        ei2, ei2 + NE, ew2, cnt2, buf2, NSB,
        omics1, Bf1, h1b, 2000, omics2, Bf2, h2b, 500);

    // ---- 3: fused encoder-spmm + attention ----
    spmm_attn<<<dim3((NN + 3) / 4), b256, 0, stream>>>(
        cnt1, buf1, h1b, cnt2, buf2, h2b, womega, uomega, e1, e2, emb, embb, alph);

    // ---- 4: decoder spmm ----
    spmm_dec<<<dim3((NN + 3) / 4), b256, 0, stream>>>(
        cnt1, buf1, cnt2, buf2, embb, s1b, s2b);

    // ---- 5: decoder GEMMs (overwrites d1/d2, incl. dead bucket region) ----
    gemm_dec4<<<dim3((NITEMS + 3) / 4), b256, 0, stream>>>(
        s1b, Wf1, d1, 2000, 125, s2b, Wf2, d2, 500, 32);
}